// Round 7
// baseline (333.126 us; speedup 1.0000x reference)
//
#include <hip/hip_runtime.h>
#include <hip/hip_bf16.h>

// Problem constants
#define BB 4
#define SS 2048
#define DD 1024
#define HH 16
#define DHH 64
#define MM (BB*SS)   // 8192 rows

typedef __bf16 bf16x8 __attribute__((ext_vector_type(8)));
typedef __bf16 bf16x4 __attribute__((ext_vector_type(4)));
typedef float  f32x4  __attribute__((ext_vector_type(4)));

__device__ __forceinline__ f32x4 mfma16(bf16x8 a, bf16x8 b, f32x4 c) {
    return __builtin_amdgcn_mfma_f32_16x16x32_bf16(a, b, c, 0, 0, 0);
}

// async global->LDS, 16B per lane. LDS dest is wave-uniform base + lane*16.
__device__ __forceinline__ void async16(const void* g, void* l) {
    __builtin_amdgcn_global_load_lds(
        (const __attribute__((address_space(1))) void*)g,
        (__attribute__((address_space(3))) void*)l, 16, 0, 0);
}

// ---------------- fp32 -> bf16 conversion (vectorized, 8 elems/thread) -----
__global__ __launch_bounds__(256) void cvt_f32_bf16(const float* __restrict__ s,
                                                    __bf16* __restrict__ d, int n8,
                                                    float scale) {
    int i = blockIdx.x * blockDim.x + threadIdx.x;
    if (i >= n8) return;
    float4 v0 = ((const float4*)s)[2*i];
    float4 v1 = ((const float4*)s)[2*i + 1];
    bf16x8 o = { (__bf16)(v0.x*scale), (__bf16)(v0.y*scale), (__bf16)(v0.z*scale), (__bf16)(v0.w*scale),
                 (__bf16)(v1.x*scale), (__bf16)(v1.y*scale), (__bf16)(v1.z*scale), (__bf16)(v1.w*scale) };
    ((bf16x8*)d)[i] = o;
}

// 4 weight matrices in one launch; blockIdx.y picks the matrix. WQ (y==0)
// carries scale log2(e)/8 so attention uses exp2 directly.
__global__ __launch_bounds__(256) void cvt_w4(const float* __restrict__ w0,
                                              const float* __restrict__ w1,
                                              const float* __restrict__ w2,
                                              const float* __restrict__ w3,
                                              __bf16* __restrict__ d0,
                                              __bf16* __restrict__ d1,
                                              __bf16* __restrict__ d2,
                                              __bf16* __restrict__ d3) {
    int i = blockIdx.x * blockDim.x + threadIdx.x;
    const float* s = blockIdx.y == 0 ? w0 : blockIdx.y == 1 ? w1 : blockIdx.y == 2 ? w2 : w3;
    __bf16* d      = blockIdx.y == 0 ? d0 : blockIdx.y == 1 ? d1 : blockIdx.y == 2 ? d2 : d3;
    float scale = blockIdx.y == 0 ? 0.125f * 1.4426950408889634f : 1.0f;
    float4 v0 = ((const float4*)s)[2*i];
    float4 v1 = ((const float4*)s)[2*i + 1];
    bf16x8 o = { (__bf16)(v0.x*scale), (__bf16)(v0.y*scale), (__bf16)(v0.z*scale), (__bf16)(v0.w*scale),
                 (__bf16)(v1.x*scale), (__bf16)(v1.y*scale), (__bf16)(v1.z*scale), (__bf16)(v1.w*scale) };
    ((bf16x8*)d)[i] = o;
}

// ---------------- GEMM: C[M][ncols] = A[M][K] * B[ncols][K]^T --------------
// 128x128 tile, BK=32, 256 threads (4 waves, 2x2), 4x4 16x16x32 frags/wave.
// PERM: permute output columns within each 64-block by pi(c)=(c&15)*4+(c>>4&3)
// (used for V^T so attention's pi-packed P rows line up with V rows).
template<typename OutT, bool PERM>
__global__ __launch_bounds__(256) void gemm_nt(const __bf16* __restrict__ A,
                                               const __bf16* __restrict__ Bb, size_t bStride,
                                               OutT* __restrict__ Cb, size_t cStride,
                                               int ncols) {
    constexpr int K = DD;
    __shared__ __bf16 As[128*32];
    __shared__ __bf16 Bs[128*32];
    const int t = threadIdx.x, l = t & 63, w = t >> 6;
    const int l15 = l & 15, g8 = (l >> 4) << 3;
    const int wm = w >> 1, wn = w & 1;
    const int m0 = blockIdx.y * 128, n0 = blockIdx.x * 128;
    const __bf16* Bp = Bb + (size_t)blockIdx.z * bStride;
    OutT* Cp = Cb + (size_t)blockIdx.z * cStride;

    f32x4 acc[4][4] = {};

    for (int k0 = 0; k0 < K; k0 += 32) {
        #pragma unroll
        for (int j = 0; j < 2; ++j) {
            int c0 = w*128 + j*64;       // wave-uniform chunk base
            int ca = c0 + l;             // lane chunk
            int row = ca >> 2, kc = (ca & 3) << 3;
            async16(A  + (size_t)(m0 + row)*K + k0 + kc, &As[c0*8]);
            async16(Bp + (size_t)(n0 + row)*K + k0 + kc, &Bs[c0*8]);
        }
        __syncthreads();   // drains vmcnt -> tiles ready
        bf16x8 af[4], bfr[4];
        #pragma unroll
        for (int mi = 0; mi < 4; ++mi)
            af[mi] = *(const bf16x8*)&As[(wm*64 + mi*16 + l15)*32 + g8];
        #pragma unroll
        for (int ni = 0; ni < 4; ++ni)
            bfr[ni] = *(const bf16x8*)&Bs[(wn*64 + ni*16 + l15)*32 + g8];
        __builtin_amdgcn_s_setprio(1);
        #pragma unroll
        for (int mi = 0; mi < 4; ++mi)
            #pragma unroll
            for (int ni = 0; ni < 4; ++ni)
                acc[mi][ni] = mfma16(af[mi], bfr[ni], acc[mi][ni]);
        __builtin_amdgcn_s_setprio(0);
        __syncthreads();   // all reads done before next stage overwrites
    }
    // epilogue: C/D layout col=lane&15, row=(lane>>4)*4+r
    #pragma unroll
    for (int mi = 0; mi < 4; ++mi)
        #pragma unroll
        for (int ni = 0; ni < 4; ++ni)
            #pragma unroll
            for (int r = 0; r < 4; ++r) {
                int row = m0 + wm*64 + mi*16 + ((l >> 4) << 2) + r;
                int col = n0 + wn*64 + ni*16 + l15;
                if (PERM) col = (col & ~63) | ((col & 15) << 2) | ((col >> 4) & 3);
                Cp[(size_t)row*ncols + col] = (OutT)acc[mi][ni][r];
            }
}

// ---------------- Flash attention v4 -----------------------------------
// Block = (b,h) x 256-row q-tile; 4 waves, wave w owns q rows [w*64, w*64+64).
// (64 q-rows/wave: K/V LDS reads amortize over 2x MFMA vs v3.)
// WQ pre-scaled by log2(e)/8 -> P = exp2(s) raw, NO max tracking; row-sum
// reduced once in epilogue. K and V^T staged via global_load_lds, double-
// buffered, one barrier/iter, XOR-swizzle via pre-swizzled global source.
// P strip pi-packed (pi(kv)=(kv&15)*4+(kv>>4)) -> ds_write_b64; V^T columns
// carry the same pi (baked into its GEMM epilogue) so PV contraction aligns.
__global__ __launch_bounds__(256) void attn_fwd(const __bf16* __restrict__ Qm,
                                                const __bf16* __restrict__ Km,
                                                const __bf16* __restrict__ Vt,
                                                __bf16* __restrict__ AO) {
    __shared__ __bf16 Kb[2][64*64];   // [kv][d], XOR-swizzled chunks
    __shared__ __bf16 Vb[2][64*64];   // [d][kv-slot], XOR-swizzled chunks
    __shared__ __bf16 Pl[4][64*64];   // per-wave P strip [q][kv-slot], swizzled
    const int t = threadIdx.x, l = t & 63, w = t >> 6;
    const int l15 = l & 15, g = l >> 4;
    const int bh = blockIdx.x, qt = blockIdx.y;   // bh%8 -> XCD
    const int b = bh >> 4, h = bh & 15;
    const size_t qbase = (size_t)b*SS + qt*256;

    const __bf16* Kbh = Km + (size_t)b*SS*DD + h*DHH;
    const __bf16* Vbh = Vt + (size_t)h*DHH*MM + (size_t)b*SS;

    // staging coords: chunk c in [0,512): LDS row c>>3, source chunk (c&7)^(row&7)
    const int ca = w*128 + l,      cb_ = w*128 + 64 + l;
    const int ra = ca >> 3,        rb = cb_ >> 3;
    const int ka = ((ca & 7) ^ (ra & 7)) << 3;
    const int kb2 = ((cb_ & 7) ^ (rb & 7)) << 3;

    // Q A-frags (global, once): row strip-local = l15, k = ks*32 + g*8
    bf16x8 qa[4][2];
    #pragma unroll
    for (int mi = 0; mi < 4; ++mi)
        #pragma unroll
        for (int ks = 0; ks < 2; ++ks)
            qa[mi][ks] = *(const bf16x8*)(Qm + (qbase + w*64 + mi*16 + l15)*DD
                                          + h*DHH + ks*32 + g*8);

    f32x4 Oacc[4][4] = {};
    float Lacc[16];
    #pragma unroll
    for (int i = 0; i < 16; ++i) Lacc[i] = 0.f;

    auto stage = [&](int kv0n, int nb) {
        async16(Kbh + (size_t)(kv0n + ra)*DD + ka, &Kb[nb][(w*128)*8]);
        async16(Kbh + (size_t)(kv0n + rb)*DD + kb2, &Kb[nb][(w*128 + 64)*8]);
        async16(Vbh + (size_t)ra*MM + kv0n + ka, &Vb[nb][(w*128)*8]);
        async16(Vbh + (size_t)rb*MM + kv0n + kb2, &Vb[nb][(w*128 + 64)*8]);
    };

    stage(0, 0);
    __syncthreads();
    int cur = 0;
    for (int it = 0; it < SS/64; ++it) {
        int nx = (it + 1 < SS/64) ? (it + 1)*64 : 0;   // last prefetch: dummy
        stage(nx, cur ^ 1);

        // ---- QK^T from LDS (swizzled reads, 2-way banks) ----
        f32x4 sf[4][4] = {};
        #pragma unroll
        for (int ni = 0; ni < 4; ++ni) {
            int r = ni*16 + l15, sw = (r & 7) << 3;
            bf16x8 k0 = *(const bf16x8*)&Kb[cur][r*64 + ((g*8) ^ sw)];
            bf16x8 k1 = *(const bf16x8*)&Kb[cur][r*64 + ((32 + g*8) ^ sw)];
            __builtin_amdgcn_s_setprio(1);
            #pragma unroll
            for (int mi = 0; mi < 4; ++mi) {
                sf[mi][ni] = mfma16(qa[mi][0], k0, sf[mi][ni]);
                sf[mi][ni] = mfma16(qa[mi][1], k1, sf[mi][ni]);
            }
            __builtin_amdgcn_s_setprio(0);
        }
        // ---- P = exp2(s); per-lane partial row sums (no shuffles) ----
        #pragma unroll
        for (int mi = 0; mi < 4; ++mi)
            #pragma unroll
            for (int ni = 0; ni < 4; ++ni)
                #pragma unroll
                for (int r = 0; r < 4; ++r) {
                    float p = __builtin_amdgcn_exp2f(sf[mi][ni][r]);
                    sf[mi][ni][r] = p;
                    Lacc[mi*4 + r] += p;
                }
        // ---- P -> pi-packed swizzled strip (16x ds_write_b64) ----
        #pragma unroll
        for (int mi = 0; mi < 4; ++mi)
            #pragma unroll
            for (int r = 0; r < 4; ++r) {
                int q = mi*16 + g*4 + r;
                bf16x4 pk = { (__bf16)sf[mi][0][r], (__bf16)sf[mi][1][r],
                              (__bf16)sf[mi][2][r], (__bf16)sf[mi][3][r] };
                *(bf16x4*)&Pl[w][q*64 + ((l15*4) ^ ((q & 7) << 3))] = pk;
            }
        bf16x8 pa[4][2];
        #pragma unroll
        for (int mi = 0; mi < 4; ++mi)
            #pragma unroll
            for (int ks = 0; ks < 2; ++ks)
                pa[mi][ks] = *(const bf16x8*)&Pl[w][(mi*16 + l15)*64
                                + ((ks*32 + g*8) ^ ((l15 & 7) << 3))];
        // ---- PV from LDS V (rows = d, cols = pi-slots) ----
        #pragma unroll
        for (int f = 0; f < 4; ++f) {
            int r = f*16 + l15, sw = (r & 7) << 3;
            bf16x8 v0 = *(const bf16x8*)&Vb[cur][r*64 + ((g*8) ^ sw)];
            bf16x8 v1 = *(const bf16x8*)&Vb[cur][r*64 + ((32 + g*8) ^ sw)];
            __builtin_amdgcn_s_setprio(1);
            #pragma unroll
            for (int mi = 0; mi < 4; ++mi) {
                Oacc[mi][f] = mfma16(pa[mi][0], v0, Oacc[mi][f]);
                Oacc[mi][f] = mfma16(pa[mi][1], v1, Oacc[mi][f]);
            }
            __builtin_amdgcn_s_setprio(0);
        }
        __syncthreads();   // stage (vmcnt) drained; buffers safe to swap
        cur ^= 1;
    }
    // ---- epilogue: finish row sums (one shuffle tree), normalize, store ----
    #pragma unroll
    for (int m = 1; m <= 8; m <<= 1)
        #pragma unroll
        for (int i = 0; i < 16; ++i)
            Lacc[i] += __shfl_xor(Lacc[i], m, 64);
    float inv[16];
    #pragma unroll
    for (int i = 0; i < 16; ++i) inv[i] = 1.0f / Lacc[i];
    #pragma unroll
    for (int mi = 0; mi < 4; ++mi)
        #pragma unroll
        for (int f = 0; f < 4; ++f)
            #pragma unroll
            for (int r = 0; r < 4; ++r) {
                size_t row = qbase + w*64 + mi*16 + g*4 + r;
                AO[row*DD + h*DHH + f*16 + l15] = (__bf16)(Oacc[mi][f][r] * inv[mi*4+r]);
            }
}

// ---------------------------------------------------------------------------
extern "C" void kernel_launch(void* const* d_in, const int* in_sizes, int n_in,
                              void* d_out, int out_size, void* d_ws, size_t ws_size,
                              hipStream_t stream) {
    const float* x  = (const float*)d_in[0];
    const float* WQ = (const float*)d_in[1];
    const float* WK = (const float*)d_in[2];
    const float* WV = (const float*)d_in[3];
    const float* WO = (const float*)d_in[4];
    float* out = (float*)d_out;

    // workspace (bf16): x | WQ WK WV WO | Q K Vt   (AO reuses x slot)
    __bf16* xbf = (__bf16*)d_ws;
    __bf16* wqb = xbf + (size_t)MM*DD;
    __bf16* wkb = wqb + (size_t)DD*DD;
    __bf16* wvb = wkb + (size_t)DD*DD;
    __bf16* wob = wvb + (size_t)DD*DD;
    __bf16* qbf = wob + (size_t)DD*DD;
    __bf16* kbf = qbf + (size_t)MM*DD;
    __bf16* vtb = kbf + (size_t)MM*DD;   // V^T: [1024][8192], pi-permuted cols
    __bf16* aobf = xbf;                  // x fully consumed before attention

    cvt_f32_bf16<<<(MM*DD/8)/256, 256, 0, stream>>>(x, xbf, MM*DD/8, 1.0f);
    cvt_w4<<<dim3((DD*DD/8)/256, 4), 256, 0, stream>>>(WQ, WK, WV, WO,
                                                       wqb, wkb, wvb, wob);

    // Q,K projections (z batches over {WQ,WK})
    gemm_nt<__bf16, false><<<dim3(DD/128, MM/128, 2), 256, 0, stream>>>(
        xbf, wqb, (size_t)DD*DD, qbf, (size_t)MM*DD, DD);

    // V^T = WV @ x^T with pi-permuted columns
    gemm_nt<__bf16, true><<<dim3(MM/128, DD/128, 1), 256, 0, stream>>>(
        wvb, xbf, 0, vtb, 0, MM);

    // attention: 256-row q-tiles
    attn_fwd<<<dim3(BB*HH, SS/256), 256, 0, stream>>>(qbf, kbf, vtb, aobf);

    // output projection -> fp32 d_out
    gemm_nt<float, false><<<dim3(DD/128, MM/128, 1), 256, 0, stream>>>(
        aobf, wob, 0, out, 0, DD);
}

// Round 8
// 331.034 us; speedup vs baseline: 1.0063x; 1.0063x over previous
//
#include <hip/hip_runtime.h>
#include <hip/hip_bf16.h>

// Problem constants
#define BB 4
#define SS 2048
#define DD 1024
#define HH 16
#define DHH 64
#define MM (BB*SS)   // 8192 rows

typedef __bf16 bf16x8 __attribute__((ext_vector_type(8)));
typedef __bf16 bf16x4 __attribute__((ext_vector_type(4)));
typedef float  f32x4  __attribute__((ext_vector_type(4)));

__device__ __forceinline__ f32x4 mfma16(bf16x8 a, bf16x8 b, f32x4 c) {
    return __builtin_amdgcn_mfma_f32_16x16x32_bf16(a, b, c, 0, 0, 0);
}

// async global->LDS, 16B per lane. LDS dest is wave-uniform base + lane*16.
__device__ __forceinline__ void async16(const void* g, void* l) {
    __builtin_amdgcn_global_load_lds(
        (const __attribute__((address_space(1))) void*)g,
        (__attribute__((address_space(3))) void*)l, 16, 0, 0);
}

// ---------------- fp32 -> bf16 conversion (vectorized, 8 elems/thread) -----
__global__ __launch_bounds__(256) void cvt_f32_bf16(const float* __restrict__ s,
                                                    __bf16* __restrict__ d, int n8,
                                                    float scale) {
    int i = blockIdx.x * blockDim.x + threadIdx.x;
    if (i >= n8) return;
    float4 v0 = ((const float4*)s)[2*i];
    float4 v1 = ((const float4*)s)[2*i + 1];
    bf16x8 o = { (__bf16)(v0.x*scale), (__bf16)(v0.y*scale), (__bf16)(v0.z*scale), (__bf16)(v0.w*scale),
                 (__bf16)(v1.x*scale), (__bf16)(v1.y*scale), (__bf16)(v1.z*scale), (__bf16)(v1.w*scale) };
    ((bf16x8*)d)[i] = o;
}

// 4 weight matrices in one launch; blockIdx.y picks the matrix. WQ (y==0)
// carries scale log2(e)/8 so attention uses exp2 directly.
__global__ __launch_bounds__(256) void cvt_w4(const float* __restrict__ w0,
                                              const float* __restrict__ w1,
                                              const float* __restrict__ w2,
                                              const float* __restrict__ w3,
                                              __bf16* __restrict__ d0,
                                              __bf16* __restrict__ d1,
                                              __bf16* __restrict__ d2,
                                              __bf16* __restrict__ d3) {
    int i = blockIdx.x * blockDim.x + threadIdx.x;
    const float* s = blockIdx.y == 0 ? w0 : blockIdx.y == 1 ? w1 : blockIdx.y == 2 ? w2 : w3;
    __bf16* d      = blockIdx.y == 0 ? d0 : blockIdx.y == 1 ? d1 : blockIdx.y == 2 ? d2 : d3;
    float scale = blockIdx.y == 0 ? 0.125f * 1.4426950408889634f : 1.0f;
    float4 v0 = ((const float4*)s)[2*i];
    float4 v1 = ((const float4*)s)[2*i + 1];
    bf16x8 o = { (__bf16)(v0.x*scale), (__bf16)(v0.y*scale), (__bf16)(v0.z*scale), (__bf16)(v0.w*scale),
                 (__bf16)(v1.x*scale), (__bf16)(v1.y*scale), (__bf16)(v1.z*scale), (__bf16)(v1.w*scale) };
    ((bf16x8*)d)[i] = o;
}

// ---------------- GEMM: C[M][ncols] = A[M][K] * B[ncols][K]^T --------------
// 128x128 tile, BK=32, 256 threads (4 waves, 2x2), 4x4 16x16x32 frags/wave.
// PERM: permute output columns within each 64-block by pi(c)=(c&15)*4+(c>>4&3)
// (used for V^T so attention's pi-packed P rows line up with V rows).
template<typename OutT, bool PERM>
__global__ __launch_bounds__(256) void gemm_nt(const __bf16* __restrict__ A,
                                               const __bf16* __restrict__ Bb, size_t bStride,
                                               OutT* __restrict__ Cb, size_t cStride,
                                               int ncols) {
    constexpr int K = DD;
    __shared__ __bf16 As[128*32];
    __shared__ __bf16 Bs[128*32];
    const int t = threadIdx.x, l = t & 63, w = t >> 6;
    const int l15 = l & 15, g8 = (l >> 4) << 3;
    const int wm = w >> 1, wn = w & 1;
    const int m0 = blockIdx.y * 128, n0 = blockIdx.x * 128;
    const __bf16* Bp = Bb + (size_t)blockIdx.z * bStride;
    OutT* Cp = Cb + (size_t)blockIdx.z * cStride;

    f32x4 acc[4][4] = {};

    for (int k0 = 0; k0 < K; k0 += 32) {
        #pragma unroll
        for (int j = 0; j < 2; ++j) {
            int c0 = w*128 + j*64;       // wave-uniform chunk base
            int ca = c0 + l;             // lane chunk
            int row = ca >> 2, kc = (ca & 3) << 3;
            async16(A  + (size_t)(m0 + row)*K + k0 + kc, &As[c0*8]);
            async16(Bp + (size_t)(n0 + row)*K + k0 + kc, &Bs[c0*8]);
        }
        __syncthreads();   // drains vmcnt -> tiles ready
        bf16x8 af[4], bfr[4];
        #pragma unroll
        for (int mi = 0; mi < 4; ++mi)
            af[mi] = *(const bf16x8*)&As[(wm*64 + mi*16 + l15)*32 + g8];
        #pragma unroll
        for (int ni = 0; ni < 4; ++ni)
            bfr[ni] = *(const bf16x8*)&Bs[(wn*64 + ni*16 + l15)*32 + g8];
        __builtin_amdgcn_s_setprio(1);
        #pragma unroll
        for (int mi = 0; mi < 4; ++mi)
            #pragma unroll
            for (int ni = 0; ni < 4; ++ni)
                acc[mi][ni] = mfma16(af[mi], bfr[ni], acc[mi][ni]);
        __builtin_amdgcn_s_setprio(0);
        __syncthreads();   // all reads done before next stage overwrites
    }
    // epilogue: C/D layout col=lane&15, row=(lane>>4)*4+r
    #pragma unroll
    for (int mi = 0; mi < 4; ++mi)
        #pragma unroll
        for (int ni = 0; ni < 4; ++ni)
            #pragma unroll
            for (int r = 0; r < 4; ++r) {
                int row = m0 + wm*64 + mi*16 + ((l >> 4) << 2) + r;
                int col = n0 + wn*64 + ni*16 + l15;
                if (PERM) col = (col & ~63) | ((col & 15) << 2) | ((col >> 4) & 3);
                Cp[(size_t)row*ncols + col] = (OutT)acc[mi][ni][r];
            }
}

// ---------------- Flash attention v5 -----------------------------------
// Block = (b,h) x 256-row q-tile; 4 waves, wave w owns q rows [w*64, w*64+64).
// WQ pre-scaled by log2(e)/8 -> P = exp2(s) raw, NO max tracking; row-sum
// reduced once in epilogue. K and V^T staged via global_load_lds, double-
// buffered, one barrier/iter, XOR-swizzle via pre-swizzled global source.
// P strip: per-wave [16][64] (8KB total, v4 was 32KB -> occupancy doubled),
// REUSED across the 4 mi-blocks: write P(mi) -> read pa(mi) immediately.
// Within-wave DS ops execute in order, so strip reuse (WAR) is safe;
// sched_barrier(0) pins compiler order. pi-packing as before.
__global__ __launch_bounds__(256) void attn_fwd(const __bf16* __restrict__ Qm,
                                                const __bf16* __restrict__ Km,
                                                const __bf16* __restrict__ Vt,
                                                __bf16* __restrict__ AO) {
    __shared__ __bf16 Kb[2][64*64];   // [kv][d], XOR-swizzled chunks (16KB)
    __shared__ __bf16 Vb[2][64*64];   // [d][kv-slot], XOR-swizzled (16KB)
    __shared__ __bf16 Pl[4][16*64];   // per-wave P strip, reused per mi (8KB)
    const int t = threadIdx.x, l = t & 63, w = t >> 6;
    const int l15 = l & 15, g = l >> 4;
    const int bh = blockIdx.x, qt = blockIdx.y;   // bh%8 -> XCD
    const int b = bh >> 4, h = bh & 15;
    const size_t qbase = (size_t)b*SS + qt*256;

    const __bf16* Kbh = Km + (size_t)b*SS*DD + h*DHH;
    const __bf16* Vbh = Vt + (size_t)h*DHH*MM + (size_t)b*SS;

    // staging coords: chunk c in [0,512): LDS row c>>3, source chunk (c&7)^(row&7)
    const int ca = w*128 + l,      cb_ = w*128 + 64 + l;
    const int ra = ca >> 3,        rb = cb_ >> 3;
    const int ka = ((ca & 7) ^ (ra & 7)) << 3;
    const int kb2 = ((cb_ & 7) ^ (rb & 7)) << 3;

    // Q A-frags (global, once): row strip-local = l15, k = ks*32 + g*8
    bf16x8 qa[4][2];
    #pragma unroll
    for (int mi = 0; mi < 4; ++mi)
        #pragma unroll
        for (int ks = 0; ks < 2; ++ks)
            qa[mi][ks] = *(const bf16x8*)(Qm + (qbase + w*64 + mi*16 + l15)*DD
                                          + h*DHH + ks*32 + g*8);

    f32x4 Oacc[4][4] = {};
    float Lacc[16];
    #pragma unroll
    for (int i = 0; i < 16; ++i) Lacc[i] = 0.f;

    auto stage = [&](int kv0n, int nb) {
        async16(Kbh + (size_t)(kv0n + ra)*DD + ka, &Kb[nb][(w*128)*8]);
        async16(Kbh + (size_t)(kv0n + rb)*DD + kb2, &Kb[nb][(w*128 + 64)*8]);
        async16(Vbh + (size_t)ra*MM + kv0n + ka, &Vb[nb][(w*128)*8]);
        async16(Vbh + (size_t)rb*MM + kv0n + kb2, &Vb[nb][(w*128 + 64)*8]);
    };

    stage(0, 0);
    __syncthreads();
    int cur = 0;
    for (int it = 0; it < SS/64; ++it) {
        int nx = (it + 1 < SS/64) ? (it + 1)*64 : 0;   // last prefetch: dummy
        stage(nx, cur ^ 1);

        // ---- QK^T from LDS (swizzled reads, 2-way banks) ----
        f32x4 sf[4][4] = {};
        #pragma unroll
        for (int ni = 0; ni < 4; ++ni) {
            int r = ni*16 + l15, sw = (r & 7) << 3;
            bf16x8 k0 = *(const bf16x8*)&Kb[cur][r*64 + ((g*8) ^ sw)];
            bf16x8 k1 = *(const bf16x8*)&Kb[cur][r*64 + ((32 + g*8) ^ sw)];
            __builtin_amdgcn_s_setprio(1);
            #pragma unroll
            for (int mi = 0; mi < 4; ++mi) {
                sf[mi][ni] = mfma16(qa[mi][0], k0, sf[mi][ni]);
                sf[mi][ni] = mfma16(qa[mi][1], k1, sf[mi][ni]);
            }
            __builtin_amdgcn_s_setprio(0);
        }
        // ---- P = exp2(s); per-lane partial row sums (no shuffles) ----
        #pragma unroll
        for (int mi = 0; mi < 4; ++mi)
            #pragma unroll
            for (int ni = 0; ni < 4; ++ni)
                #pragma unroll
                for (int r = 0; r < 4; ++r) {
                    float p = __builtin_amdgcn_exp2f(sf[mi][ni][r]);
                    sf[mi][ni][r] = p;
                    Lacc[mi*4 + r] += p;
                }
        // ---- P -> strip -> A-frags, per mi (strip reused, in-order DS) ----
        bf16x8 pa[4][2];
        #pragma unroll
        for (int mi = 0; mi < 4; ++mi) {
            #pragma unroll
            for (int r = 0; r < 4; ++r) {
                int q = g*4 + r;
                bf16x4 pk = { (__bf16)sf[mi][0][r], (__bf16)sf[mi][1][r],
                              (__bf16)sf[mi][2][r], (__bf16)sf[mi][3][r] };
                *(bf16x4*)&Pl[w][q*64 + ((l15*4) ^ ((q & 7) << 3))] = pk;
            }
            #pragma unroll
            for (int ks = 0; ks < 2; ++ks)
                pa[mi][ks] = *(const bf16x8*)&Pl[w][l15*64
                                + ((ks*32 + g*8) ^ ((l15 & 7) << 3))];
            __builtin_amdgcn_sched_barrier(0);  // pin write(mi+1) after read(mi)
        }
        // ---- PV from LDS V (rows = d, cols = pi-slots) ----
        #pragma unroll
        for (int f = 0; f < 4; ++f) {
            int r = f*16 + l15, sw = (r & 7) << 3;
            bf16x8 v0 = *(const bf16x8*)&Vb[cur][r*64 + ((g*8) ^ sw)];
            bf16x8 v1 = *(const bf16x8*)&Vb[cur][r*64 + ((32 + g*8) ^ sw)];
            __builtin_amdgcn_s_setprio(1);
            #pragma unroll
            for (int mi = 0; mi < 4; ++mi) {
                Oacc[mi][f] = mfma16(pa[mi][0], v0, Oacc[mi][f]);
                Oacc[mi][f] = mfma16(pa[mi][1], v1, Oacc[mi][f]);
            }
            __builtin_amdgcn_s_setprio(0);
        }
        __syncthreads();   // stage (vmcnt) drained; buffers safe to swap
        cur ^= 1;
    }
    // ---- epilogue: finish row sums (one shuffle tree), normalize, store ----
    #pragma unroll
    for (int m = 1; m <= 8; m <<= 1)
        #pragma unroll
        for (int i = 0; i < 16; ++i)
            Lacc[i] += __shfl_xor(Lacc[i], m, 64);
    float inv[16];
    #pragma unroll
    for (int i = 0; i < 16; ++i) inv[i] = 1.0f / Lacc[i];
    #pragma unroll
    for (int mi = 0; mi < 4; ++mi)
        #pragma unroll
        for (int f = 0; f < 4; ++f)
            #pragma unroll
            for (int r = 0; r < 4; ++r) {
                size_t row = qbase + w*64 + mi*16 + g*4 + r;
                AO[row*DD + h*DHH + f*16 + l15] = (__bf16)(Oacc[mi][f][r] * inv[mi*4+r]);
            }
}

// ---------------------------------------------------------------------------
extern "C" void kernel_launch(void* const* d_in, const int* in_sizes, int n_in,
                              void* d_out, int out_size, void* d_ws, size_t ws_size,
                              hipStream_t stream) {
    const float* x  = (const float*)d_in[0];
    const float* WQ = (const float*)d_in[1];
    const float* WK = (const float*)d_in[2];
    const float* WV = (const float*)d_in[3];
    const float* WO = (const float*)d_in[4];
    float* out = (float*)d_out;

    // workspace (bf16): x | WQ WK WV WO | Q K Vt   (AO reuses x slot)
    __bf16* xbf = (__bf16*)d_ws;
    __bf16* wqb = xbf + (size_t)MM*DD;
    __bf16* wkb = wqb + (size_t)DD*DD;
    __bf16* wvb = wkb + (size_t)DD*DD;
    __bf16* wob = wvb + (size_t)DD*DD;
    __bf16* qbf = wob + (size_t)DD*DD;
    __bf16* kbf = qbf + (size_t)MM*DD;
    __bf16* vtb = kbf + (size_t)MM*DD;   // V^T: [1024][8192], pi-permuted cols
    __bf16* aobf = xbf;                  // x fully consumed before attention

    cvt_f32_bf16<<<(MM*DD/8)/256, 256, 0, stream>>>(x, xbf, MM*DD/8, 1.0f);
    cvt_w4<<<dim3((DD*DD/8)/256, 4), 256, 0, stream>>>(WQ, WK, WV, WO,
                                                       wqb, wkb, wvb, wob);

    // Q,K projections (z batches over {WQ,WK})
    gemm_nt<__bf16, false><<<dim3(DD/128, MM/128, 2), 256, 0, stream>>>(
        xbf, wqb, (size_t)DD*DD, qbf, (size_t)MM*DD, DD);

    // V^T = WV @ x^T with pi-permuted columns
    gemm_nt<__bf16, true><<<dim3(MM/128, DD/128, 1), 256, 0, stream>>>(
        wvb, xbf, 0, vtb, 0, MM);

    // attention: 256-row q-tiles
    attn_fwd<<<dim3(BB*HH, SS/256), 256, 0, stream>>>(qbf, kbf, vtb, aobf);

    // output projection -> fp32 d_out
    gemm_nt<float, false><<<dim3(DD/128, MM/128, 1), 256, 0, stream>>>(
        aobf, wob, 0, out, 0, DD);
}